// Round 20
// baseline (1263.346 us; speedup 1.0000x reference)
//
#include <hip/hip_runtime.h>
#include <hip/hip_bf16.h>

typedef __bf16 bf16;
typedef __bf16 bf16x8 __attribute__((ext_vector_type(8)));
typedef __bf16 bf16x4 __attribute__((ext_vector_type(4)));
typedef float f32x4 __attribute__((ext_vector_type(4)));

#define T_SEQ 80
#define NB 128
#define NT 512
#define U 1024
#define U3 3072

// ws byte offsets
#define WT_OFF   0ull                  // 3*3072*1024*2 = 18874368
#define WXT_OFF  18874368ull           // 3072*128*2    = 786432
#define XG_OFF   19660800ull           // 80*128*128*2  = 2621440
#define GX1_OFF  22282240ull           // 80*3072*128*2 = 62914560
#define H0B_OFF  85196800ull           // 81 * 128*1024*2 = 21233664 (deep buffers)
#define H1B_OFF  106430464ull          // 21233664
#define CNT_OFF  127664128ull          // barrier counters (2048 B)
#define WS_NEED  127666176ull

#define HBUF_ELEMS 131072ull           // 128*1024 bf16 per h buffer

// h buffers use a TILED layout so each wave's A-fragment load is ONE contiguous
// 1KB segment:  elem(row, col) at (row>>4)*16384 + (col>>5)*512 + (row&15)*32 + (col&31)

#define LDS_SX2_OFF   147456                  // after 72*1024 bf16 weight slots
#define LDS_RED_OFF   (147456 + 24*132*4)     // after Sx2[24][132] f32
#define LDS_BYTES     (LDS_RED_OFF + 64)      // = 160192 <= 163840

__device__ __forceinline__ float sigmoidf_(float x) { return 1.f / (1.f + __expf(-x)); }

__global__ void k_embed(const int* __restrict__ tok, const float* __restrict__ E,
                        bf16* __restrict__ Xg) {
  int idx = blockIdx.x * 256 + threadIdx.x;   // over 80*128*128, layout [t][b][k]
  int k = idx & 127;
  int bt = idx >> 7;
  int b = bt & 127;
  int t = bt >> 7;
  float v = 0.f;
  if (k < 100) v = E[(size_t)tok[b * 80 + t] * 100 + k];
  Xg[idx] = (bf16)v;
}

__global__ void k_trans(const float* __restrict__ Wh1, const float* __restrict__ Wx2,
                        const float* __restrict__ Wh2, bf16* __restrict__ WT) {
  __shared__ float tile[32][33];
  const float* src = (blockIdx.z == 0) ? Wh1 : (blockIdx.z == 1) ? Wx2 : Wh2;
  int cb = blockIdx.x * 32, kb = blockIdx.y * 32;
  int tx = threadIdx.x, ty = threadIdx.y;
  for (int i = ty; i < 32; i += 8) tile[i][tx] = src[(size_t)(kb + i) * U3 + cb + tx];
  __syncthreads();
  bf16* dst = WT + (size_t)blockIdx.z * U3 * U;  // [col][k] bf16
  for (int i = ty; i < 32; i += 8) dst[(size_t)(cb + i) * U + kb + tx] = (bf16)tile[tx][i];
}

__global__ void k_wxt(const float* __restrict__ Wx1, bf16* __restrict__ WXT) {
  __shared__ float tile[32][33];
  int cb = blockIdx.x * 32, kb = blockIdx.y * 32;
  int tx = threadIdx.x, ty = threadIdx.y;
  for (int i = ty; i < 32; i += 8) {
    int k = kb + i;
    tile[i][tx] = (k < 100) ? Wx1[(size_t)k * U3 + cb + tx] : 0.f;
  }
  __syncthreads();
  for (int i = ty; i < 32; i += 8) WXT[(size_t)(cb + i) * 128 + kb + tx] = (bf16)tile[tx][i];
}

// GX1[t][col][b] = (x_t @ Wx1 + bx1), bf16, col-major over batch
__global__ __launch_bounds__(256) void k_gx1(const bf16* __restrict__ Xg,
                                             const bf16* __restrict__ WXT,
                                             const float* __restrict__ bx1,
                                             bf16* __restrict__ GX1) {
  int mb = blockIdx.x * 64, nb = blockIdx.y * 64;
  int w = threadIdx.x >> 6, l = threadIdx.x & 63;
  int lr = l & 15, lq = l >> 4;
  int rowA = mb + w * 16 + lr;                 // m = t*128 + b
  int tA = rowA >> 7, bA = rowA & 127;
  const bf16* aptr = Xg + ((size_t)tA * 128 + bA) * 128 + lq * 8;
  f32x4 acc[4] = {};
  #pragma unroll
  for (int ks = 0; ks < 4; ++ks) {
    bf16x8 a = *(const bf16x8*)(aptr + ks * 32);
    #pragma unroll
    for (int nt = 0; nt < 4; ++nt) {
      int col = nb + nt * 16 + lr;
      bf16x8 b = *(const bf16x8*)(WXT + (size_t)col * 128 + ks * 32 + lq * 8);
      acc[nt] = __builtin_amdgcn_mfma_f32_16x16x32_bf16(a, b, acc[nt], 0, 0, 0);
    }
  }
  int m0 = mb + w * 16 + lq * 4;
  int t0 = m0 >> 7, b0 = m0 & 127;
  #pragma unroll
  for (int nt = 0; nt < 4; ++nt) {
    int col = nb + nt * 16 + lr;
    float bias = bx1[col];
    bf16x4 o;
    #pragma unroll
    for (int j = 0; j < 4; ++j) o[j] = (bf16)(acc[nt][j] + bias);
    *(bf16x4*)(GX1 + ((size_t)t0 * U3 + col) * 128 + b0) = o;
  }
}

// Weight slot layout (72 slots x 1024 bf16, 16B-granule XOR-swizzled):
//   sid  0-15: Wh1 z(0-7) r(8-15)
//   sid 16-31: Wx2 z(0-7) r(8-15)
//   sid 32-55: Wh2 z(0-7) r(8-15) n(16-23)
//   sid 56-71: combined n: 56-63 = Wh1 n-cols, 64-71 = Wx2 n-cols
__device__ __forceinline__ bf16x8 ldsw(const bf16* Wlds, int sid, int k8) {
  return *(const bf16x8*)(Wlds + ((size_t)sid << 10) + ((k8 ^ (sid & 7) ^ (sid & 8)) << 3));
}

// Packed-pair h store: even/odd lane pair holds adjacent columns, same row.
// Agent-scope relaxed atomic store -> data lands at the coherence point (IF).
__device__ __forceinline__ void st_pair(bf16* dst_even, int lr, float h) {
  bf16 hb16 = (bf16)h;
  unsigned hb = (unsigned)__builtin_bit_cast(unsigned short, hb16);
  unsigned pb = (unsigned)__shfl_xor((int)hb, 1) & 0xffffu;
  if (!(lr & 1)) {
    unsigned v = hb | (pb << 16);
    __hip_atomic_store((unsigned*)dst_even, v, __ATOMIC_RELAXED, __HIP_MEMORY_SCOPE_AGENT);
  }
}

// Fence-free tree barrier (measured ~1.67 us/barrier at 128 blocks).
__device__ void gridbar(int* cnt, int i) {
  __syncthreads();
  if (threadIdx.x == 0) {
    int* gc   = cnt + (blockIdx.x & 7) * 32;   // 128B apart
    int* root = cnt + 256;
    int* go   = cnt + 288;
    int old = __hip_atomic_fetch_add(gc, 1, __ATOMIC_RELAXED, __HIP_MEMORY_SCOPE_AGENT);
    if (old == 16 * (i + 1) - 1) {             // group leader this iteration
      int r = __hip_atomic_fetch_add(root, 1, __ATOMIC_RELAXED, __HIP_MEMORY_SCOPE_AGENT);
      if (r == 8 * (i + 1) - 1)
        __hip_atomic_store(go, i + 1, __ATOMIC_RELAXED, __HIP_MEMORY_SCOPE_AGENT);
    }
    while (__hip_atomic_load(go, __ATOMIC_RELAXED, __HIP_MEMORY_SCOPE_AGENT) < i + 1)
      __builtin_amdgcn_s_sleep(4);
  }
  __syncthreads();
}

// NT=512, 8 waves, 2/SIMD: waves 0-3 = h0 rows 32w (mt=2 x 16-row tiles, B-reads
// SHARED across mt -> per-CU ds_read halves vs r19); waves 4-7 = h1.
// Tiled h layout keeps every A-load one contiguous 1KB burst.
__global__ __launch_bounds__(NT, 1) void k_main(
    const bf16* __restrict__ WT, const bf16* __restrict__ GX1,
    bf16* __restrict__ h0b, bf16* __restrict__ h1b, int* __restrict__ cnt,
    const float* __restrict__ bh1, const float* __restrict__ bx2,
    const float* __restrict__ bh2, const float* __restrict__ Wf,
    const float* __restrict__ bfp, float* __restrict__ out) {
  extern __shared__ char lds[];
  bf16* Wlds = (bf16*)lds;
  float* Sx2 = (float*)(lds + LDS_SX2_OFF);   // [24][132] f32: gx2 handoff
  float* red = (float*)(lds + LDS_RED_OFF);   // 8 floats

  const int tid = threadIdx.x;
  const int w = tid >> 6, l = tid & 63;
  const int lr = l & 15, lq = l >> 4;
  const int c0 = blockIdx.x * 8;              // this block's h-column base
  const int koff = ((blockIdx.x >> 3) & 15) * 2;  // XCD-local K-walk stagger

  // tiled-layout write base offset for this block's columns
  const int wr_kq = (c0 >> 5) * 512 + (c0 & 31);

  // ---- stage 72 weight slots into LDS (bf16, k-contiguous, XOR-swizzled) ----
  for (int u = tid; u < 9216; u += NT) {      // 72 slots * 128 granules
    int chunk = u & 127;
    int sid = u >> 7;
    int mat, gcol;
    if (sid < 16)      { mat = 0; gcol = c0 + (sid & 7) + ((sid >> 3) << 10); }
    else if (sid < 32) { int s = sid - 16; mat = 1; gcol = c0 + (s & 7) + ((s >> 3) << 10); }
    else if (sid < 56) { int s = sid - 32; mat = 2; gcol = c0 + (s & 7) + ((s >> 3) << 10); }
    else               { int s = sid - 56; mat = (s < 8) ? 0 : 1; gcol = 2 * U + c0 + (s & 7); }
    bf16x8 v = *(const bf16x8*)(WT + ((size_t)mat * U3 + gcol) * U + chunk * 8);
    *(bf16x8*)(Wlds + ((size_t)sid << 10) + ((chunk ^ (sid & 7) ^ (sid & 8)) << 3)) = v;
  }
  __syncthreads();

  // ---- per-lane biases ----
  const int zr_idx = (lr < 8) ? (c0 + lr) : (U + c0 + lr - 8);
  const int n_idx = 2 * U + c0 + (lr & 7);
  const float bzr1 = bh1[zr_idx];
  const float bhn1 = bh1[n_idx];
  const float bzr2 = bx2[zr_idx] + bh2[zr_idx];
  const float bxn2 = bx2[n_idx];
  const float bhn2 = bh2[n_idx];

  float hm[8];                                // fp32 master state (2 mt x 4 j)
  #pragma unroll
  for (int q = 0; q < 8; ++q) hm[q] = 0.f;

  for (int i = 0; i <= T_SEQ; ++i) {
    // deep buffers: iter i reads h0b[i], h1b[i-1]; writes h0b[i+1], h1b[i].
    const bf16* h0r = h0b + (size_t)i * HBUF_ELEMS;
    const bf16* h1r = h1b + (size_t)(i > 0 ? i - 1 : 0) * HBUF_ELEMS;
    bf16* h0w = h0b + (size_t)(i + 1) * HBUF_ELEMS;
    bf16* h1w = h1b + (size_t)i * HBUF_ELEMS;

    f32x4 a3zr[2] = {}, a3n[2] = {};

    if (w < 4) {
      // ===== h0-waves: gh1-zr + gx2-zr + combined-n, 2 row-tiles, shared B =====
      f32x4 a1zr[2] = {}, a2zr[2] = {}, an[2] = {};

      // hoist GX1 gate loads (precomputed, barrier-independent)
      bf16x4 g4p[2] = {}, gnp[2] = {};
      if (i < T_SEQ) {
        const bf16* gx = GX1 + (size_t)i * U3 * 128;
        #pragma unroll
        for (int mt = 0; mt < 2; ++mt) {
          int r0 = w * 32 + mt * 16 + lq * 4;
          g4p[mt] = *(const bf16x4*)(gx + (size_t)zr_idx * 128 + r0);
          gnp[mt] = *(const bf16x4*)(gx + (size_t)(2 * U + c0 + (lr & 7)) * 128 + r0);
        }
      }

      // tiled layout: wave w owns tiles 2w and 2w+1
      const bf16* abase = h0r + (w * 2) * 16384 + lr * 32 + lq * 8;
      #pragma unroll 8
      for (int ks = 0; ks < 32; ++ks) {
        int kss = (ks + koff) & 31;            // XCD-local staggered K-walk
        bf16x8 A0 = *(const bf16x8*)(abase + kss * 512);
        bf16x8 A1 = *(const bf16x8*)(abase + 16384 + kss * 512);
        int k8 = kss * 4 + lq;
        bf16x8 B1zr = ldsw(Wlds, lr, k8);
        bf16x8 B2zr = ldsw(Wlds, 16 + lr, k8);
        bf16x8 Bn   = ldsw(Wlds, 56 + lr, k8);   // lr<8: Wh1-n, lr>=8: Wx2-n
        a1zr[0] = __builtin_amdgcn_mfma_f32_16x16x32_bf16(A0, B1zr, a1zr[0], 0, 0, 0);
        a2zr[0] = __builtin_amdgcn_mfma_f32_16x16x32_bf16(A0, B2zr, a2zr[0], 0, 0, 0);
        an[0]   = __builtin_amdgcn_mfma_f32_16x16x32_bf16(A0, Bn,   an[0],   0, 0, 0);
        a1zr[1] = __builtin_amdgcn_mfma_f32_16x16x32_bf16(A1, B1zr, a1zr[1], 0, 0, 0);
        a2zr[1] = __builtin_amdgcn_mfma_f32_16x16x32_bf16(A1, B2zr, a2zr[1], 0, 0, 0);
        an[1]   = __builtin_amdgcn_mfma_f32_16x16x32_bf16(A1, Bn,   an[1],   0, 0, 0);
      }
      // deposit gx2 for the h1-waves: zr from all lanes, n from lanes lr>=8
      #pragma unroll
      for (int mt = 0; mt < 2; ++mt) {
        int r0 = w * 32 + mt * 16 + lq * 4;
        *(f32x4*)(Sx2 + lr * 132 + r0) = a2zr[mt];
        if (lr >= 8) *(f32x4*)(Sx2 + (16 + (lr - 8)) * 132 + r0) = an[mt];
      }
      // h0 update: H0[i] = GRU1(H0[i-1], x[i])
      if (i < T_SEQ) {
        #pragma unroll
        for (int mt = 0; mt < 2; ++mt) {
          f32x4 sv;
          #pragma unroll
          for (int j = 0; j < 4; ++j) sv[j] = sigmoidf_(a1zr[mt][j] + bzr1 + (float)g4p[mt][j]);
          f32x4 rv;
          #pragma unroll
          for (int j = 0; j < 4; ++j) rv[j] = __shfl_xor(sv[j], 8);
          if (lr < 8) {
            #pragma unroll
            for (int j = 0; j < 4; ++j) {
              float nn = tanhf((float)gnp[mt][j] + rv[j] * (an[mt][j] + bhn1));
              float z = sv[j];
              float h = z * hm[mt * 4 + j] + (1.f - z) * nn;
              hm[mt * 4 + j] = h;
              // tiled write: tile 2w+mt, row-in-tile lq*4+j
              st_pair(h0w + (w * 2 + mt) * 16384 + wr_kq + (lq * 4 + j) * 32 + (lr & ~1), lr, h);
            }
          }
        }
      }
    } else if (i > 0) {
      // ===== h1-waves: gh2 = H1[i-2]@Wh2, 2 row-tiles, shared B =====
      const bf16* abase = h1r + ((w - 4) * 2) * 16384 + lr * 32 + lq * 8;
      #pragma unroll 8
      for (int ks = 0; ks < 32; ++ks) {
        int kss = (ks + koff) & 31;
        bf16x8 A0 = *(const bf16x8*)(abase + kss * 512);
        bf16x8 A1 = *(const bf16x8*)(abase + 16384 + kss * 512);
        int k8 = kss * 4 + lq;
        bf16x8 B3zr = ldsw(Wlds, 32 + lr, k8);
        bf16x8 B3n  = ldsw(Wlds, 48 + (lr & 7), k8);
        a3zr[0] = __builtin_amdgcn_mfma_f32_16x16x32_bf16(A0, B3zr, a3zr[0], 0, 0, 0);
        a3n[0]  = __builtin_amdgcn_mfma_f32_16x16x32_bf16(A0, B3n,  a3n[0], 0, 0, 0);
        a3zr[1] = __builtin_amdgcn_mfma_f32_16x16x32_bf16(A1, B3zr, a3zr[1], 0, 0, 0);
        a3n[1]  = __builtin_amdgcn_mfma_f32_16x16x32_bf16(A1, B3n,  a3n[1], 0, 0, 0);
      }
    }
    __syncthreads();   // gx2 handoff visible to h1-waves
    if (w >= 4 && i > 0) {
      // h1 update: H1[i-1] = GRU2(H1[i-2], H0[i-1])
      #pragma unroll
      for (int mt = 0; mt < 2; ++mt) {
        int r0 = (w - 4) * 32 + mt * 16 + lq * 4;
        f32x4 sv;
        #pragma unroll
        for (int j = 0; j < 4; ++j)
          sv[j] = sigmoidf_(a3zr[mt][j] + bzr2 + Sx2[lr * 132 + r0 + j]);
        f32x4 rv;
        #pragma unroll
        for (int j = 0; j < 4; ++j) rv[j] = __shfl_xor(sv[j], 8);
        if (lr < 8) {
          #pragma unroll
          for (int j = 0; j < 4; ++j) {
            float xn = Sx2[(16 + lr) * 132 + r0 + j] + bxn2;
            float nn = tanhf(xn + rv[j] * (a3n[mt][j] + bhn2));
            float z = sv[j];
            float h = z * hm[mt * 4 + j] + (1.f - z) * nn;
            hm[mt * 4 + j] = h;
            st_pair(h1w + ((w - 4) * 2 + mt) * 16384 + wr_kq + (lq * 4 + j) * 32 + (lr & ~1), lr, h);
          }
        }
      }
    }
    gridbar(cnt, i);
  }

  // ---- final dense head: out[b] = sigmoid(H1[79] . Wf + bf), block b ----
  {
    const bf16* h1f = h1b + (size_t)T_SEQ * HBUF_ELEMS;
    const int b = blockIdx.x;
    float part = 0.f;
    if (tid < 256) {
      int k0 = tid * 4;
      // tiled layout: elem(b, k0) at (b>>4)*16384 + (k0>>5)*512 + (b&15)*32 + (k0&31)
      const bf16* p = h1f + (b >> 4) * 16384 + (k0 >> 5) * 512 + (b & 15) * 32 + (k0 & 31);
      bf16x4 hv = *(const bf16x4*)p;
      #pragma unroll
      for (int j = 0; j < 4; ++j) part += (float)hv[j] * Wf[k0 + j];
    }
    #pragma unroll
    for (int off = 32; off > 0; off >>= 1) part += __shfl_down(part, off);
    if (l == 0) red[w] = part;
    __syncthreads();
    if (tid == 0) {
      float s = bfp[0];
      #pragma unroll
      for (int q = 0; q < 8; ++q) s += red[q];
      out[blockIdx.x] = sigmoidf_(s);
    }
  }
}

extern "C" void kernel_launch(void* const* d_in, const int* in_sizes, int n_in,
                              void* d_out, int out_size, void* d_ws, size_t ws_size,
                              hipStream_t stream) {
  if (ws_size < WS_NEED) return;  // workspace insufficient -> deliberate clean fail
  const int*   tok = (const int*)d_in[0];
  const float* E   = (const float*)d_in[1];
  const float* Wx1 = (const float*)d_in[2];
  const float* Wh1 = (const float*)d_in[3];
  const float* bx1 = (const float*)d_in[4];
  const float* bh1 = (const float*)d_in[5];
  const float* Wx2 = (const float*)d_in[6];
  const float* Wh2 = (const float*)d_in[7];
  const float* bx2 = (const float*)d_in[8];
  const float* bh2 = (const float*)d_in[9];
  const float* Wf  = (const float*)d_in[10];
  const float* bfp = (const float*)d_in[11];
  char* ws = (char*)d_ws;
  bf16* WT   = (bf16*)(ws + WT_OFF);
  bf16* WXT  = (bf16*)(ws + WXT_OFF);
  bf16* Xg   = (bf16*)(ws + XG_OFF);
  bf16* GX1  = (bf16*)(ws + GX1_OFF);
  bf16* h0b  = (bf16*)(ws + H0B_OFF);
  bf16* h1b  = (bf16*)(ws + H1B_OFF);
  int*  cnt  = (int*)(ws + CNT_OFF);

  // zero only what's read-before-write: h0b[0], h1b[0], counters
  hipMemsetAsync(ws + H0B_OFF, 0, 262144, stream);
  hipMemsetAsync(ws + H1B_OFF, 0, 262144, stream);
  hipMemsetAsync(ws + CNT_OFF, 0, 2048, stream);
  k_embed<<<dim3(5120), dim3(256), 0, stream>>>(tok, E, Xg);
  k_trans<<<dim3(96, 32, 3), dim3(32, 8), 0, stream>>>(Wh1, Wx2, Wh2, WT);
  k_wxt<<<dim3(96, 4), dim3(32, 8), 0, stream>>>(Wx1, WXT);
  k_gx1<<<dim3(160, 48), dim3(256), 0, stream>>>(Xg, WXT, bx1, GX1);
  hipFuncSetAttribute((const void*)k_main, hipFuncAttributeMaxDynamicSharedMemorySize, LDS_BYTES);
  k_main<<<dim3(NB), dim3(NT), LDS_BYTES, stream>>>(WT, GX1, h0b, h1b, cnt,
                                                    bh1, bx2, bh2, Wf, bfp, (float*)d_out);
}

// Round 21
// 1008.709 us; speedup vs baseline: 1.2524x; 1.2524x over previous
//
#include <hip/hip_runtime.h>
#include <hip/hip_bf16.h>

typedef __bf16 bf16;
typedef __bf16 bf16x8 __attribute__((ext_vector_type(8)));
typedef __bf16 bf16x4 __attribute__((ext_vector_type(4)));
typedef float f32x4 __attribute__((ext_vector_type(4)));

#define T_SEQ 80
#define NB 128
#define NT 1024
#define U 1024
#define U3 3072

// ws byte offsets
#define WT_OFF   0ull                  // 3*3072*1024*2 = 18874368
#define WXT_OFF  18874368ull           // 3072*128*2    = 786432
#define XG_OFF   19660800ull           // 80*128*128*2  = 2621440
#define GX1_OFF  22282240ull           // 80*3072*128*2 = 62914560
#define H0B_OFF  85196800ull           // 81 * 128*1024*2 = 21233664 (deep buffers)
#define H1B_OFF  106430464ull          // 21233664
#define CNT_OFF  127664128ull          // barrier counters (2048 B)
#define WS_NEED  127666176ull

#define HBUF_ELEMS 131072ull           // 128*1024 bf16 per h buffer

// h buffers use a TILED layout so each wave's A-fragment load is ONE contiguous
// 1KB segment (row-major cost 16 disjoint 64B segments/load):
//   elem(row, col) at  (row>>4)*16384 + (col>>5)*512 + (row&15)*32 + (col&31)

#define LDS_SX2_OFF   147456                  // after 72*1024 bf16 weight slots
#define LDS_RED_OFF   (147456 + 24*132*4)     // after Sx2[24][132] f32
#define LDS_BYTES     (LDS_RED_OFF + 64)      // = 160192 <= 163840

__device__ __forceinline__ float sigmoidf_(float x) { return 1.f / (1.f + __expf(-x)); }

__global__ void k_embed(const int* __restrict__ tok, const float* __restrict__ E,
                        bf16* __restrict__ Xg) {
  int idx = blockIdx.x * 256 + threadIdx.x;   // over 80*128*128, layout [t][b][k]
  int k = idx & 127;
  int bt = idx >> 7;
  int b = bt & 127;
  int t = bt >> 7;
  float v = 0.f;
  if (k < 100) v = E[(size_t)tok[b * 80 + t] * 100 + k];
  Xg[idx] = (bf16)v;
}

__global__ void k_trans(const float* __restrict__ Wh1, const float* __restrict__ Wx2,
                        const float* __restrict__ Wh2, bf16* __restrict__ WT) {
  __shared__ float tile[32][33];
  const float* src = (blockIdx.z == 0) ? Wh1 : (blockIdx.z == 1) ? Wx2 : Wh2;
  int cb = blockIdx.x * 32, kb = blockIdx.y * 32;
  int tx = threadIdx.x, ty = threadIdx.y;
  for (int i = ty; i < 32; i += 8) tile[i][tx] = src[(size_t)(kb + i) * U3 + cb + tx];
  __syncthreads();
  bf16* dst = WT + (size_t)blockIdx.z * U3 * U;  // [col][k] bf16
  for (int i = ty; i < 32; i += 8) dst[(size_t)(cb + i) * U + kb + tx] = (bf16)tile[tx][i];
}

__global__ void k_wxt(const float* __restrict__ Wx1, bf16* __restrict__ WXT) {
  __shared__ float tile[32][33];
  int cb = blockIdx.x * 32, kb = blockIdx.y * 32;
  int tx = threadIdx.x, ty = threadIdx.y;
  for (int i = ty; i < 32; i += 8) {
    int k = kb + i;
    tile[i][tx] = (k < 100) ? Wx1[(size_t)k * U3 + cb + tx] : 0.f;
  }
  __syncthreads();
  for (int i = ty; i < 32; i += 8) WXT[(size_t)(cb + i) * 128 + kb + tx] = (bf16)tile[tx][i];
}

// GX1[t][col][b] = (x_t @ Wx1 + bx1), bf16, col-major over batch
__global__ __launch_bounds__(256) void k_gx1(const bf16* __restrict__ Xg,
                                             const bf16* __restrict__ WXT,
                                             const float* __restrict__ bx1,
                                             bf16* __restrict__ GX1) {
  int mb = blockIdx.x * 64, nb = blockIdx.y * 64;
  int w = threadIdx.x >> 6, l = threadIdx.x & 63;
  int lr = l & 15, lq = l >> 4;
  int rowA = mb + w * 16 + lr;                 // m = t*128 + b
  int tA = rowA >> 7, bA = rowA & 127;
  const bf16* aptr = Xg + ((size_t)tA * 128 + bA) * 128 + lq * 8;
  f32x4 acc[4] = {};
  #pragma unroll
  for (int ks = 0; ks < 4; ++ks) {
    bf16x8 a = *(const bf16x8*)(aptr + ks * 32);
    #pragma unroll
    for (int nt = 0; nt < 4; ++nt) {
      int col = nb + nt * 16 + lr;
      bf16x8 b = *(const bf16x8*)(WXT + (size_t)col * 128 + ks * 32 + lq * 8);
      acc[nt] = __builtin_amdgcn_mfma_f32_16x16x32_bf16(a, b, acc[nt], 0, 0, 0);
    }
  }
  int m0 = mb + w * 16 + lq * 4;
  int t0 = m0 >> 7, b0 = m0 & 127;
  #pragma unroll
  for (int nt = 0; nt < 4; ++nt) {
    int col = nb + nt * 16 + lr;
    float bias = bx1[col];
    bf16x4 o;
    #pragma unroll
    for (int j = 0; j < 4; ++j) o[j] = (bf16)(acc[nt][j] + bias);
    *(bf16x4*)(GX1 + ((size_t)t0 * U3 + col) * 128 + b0) = o;
  }
}

// Weight slot layout (72 slots x 1024 bf16, 16B-granule XOR-swizzled):
//   sid  0-15: Wh1 z(0-7) r(8-15)
//   sid 16-31: Wx2 z(0-7) r(8-15)
//   sid 32-55: Wh2 z(0-7) r(8-15) n(16-23)
//   sid 56-71: combined n: 56-63 = Wh1 n-cols, 64-71 = Wx2 n-cols
__device__ __forceinline__ bf16x8 ldsw(const bf16* Wlds, int sid, int k8) {
  return *(const bf16x8*)(Wlds + ((size_t)sid << 10) + ((k8 ^ (sid & 7) ^ (sid & 8)) << 3));
}

// Packed-pair h store: even/odd lane pair holds adjacent columns, same row.
// Agent-scope relaxed atomic store -> data lands at the coherence point (IF).
__device__ __forceinline__ void st_pair(bf16* dst_even, int lr, float h) {
  bf16 hb16 = (bf16)h;
  unsigned hb = (unsigned)__builtin_bit_cast(unsigned short, hb16);
  unsigned pb = (unsigned)__shfl_xor((int)hb, 1) & 0xffffu;
  if (!(lr & 1)) {
    unsigned v = hb | (pb << 16);
    __hip_atomic_store((unsigned*)dst_even, v, __ATOMIC_RELAXED, __HIP_MEMORY_SCOPE_AGENT);
  }
}

// Fence-free tree barrier (measured ~1.67 us/barrier at 128 blocks).
__device__ void gridbar(int* cnt, int i) {
  __syncthreads();
  if (threadIdx.x == 0) {
    int* gc   = cnt + (blockIdx.x & 7) * 32;   // 128B apart
    int* root = cnt + 256;
    int* go   = cnt + 288;
    int old = __hip_atomic_fetch_add(gc, 1, __ATOMIC_RELAXED, __HIP_MEMORY_SCOPE_AGENT);
    if (old == 16 * (i + 1) - 1) {             // group leader this iteration
      int r = __hip_atomic_fetch_add(root, 1, __ATOMIC_RELAXED, __HIP_MEMORY_SCOPE_AGENT);
      if (r == 8 * (i + 1) - 1)
        __hip_atomic_store(go, i + 1, __ATOMIC_RELAXED, __HIP_MEMORY_SCOPE_AGENT);
    }
    while (__hip_atomic_load(go, __ATOMIC_RELAXED, __HIP_MEMORY_SCOPE_AGENT) < i + 1)
      __builtin_amdgcn_s_sleep(4);
  }
  __syncthreads();
}

// NT=1024: waves 0-7 = h0 (gh1 + gx2 + combined-n, 16 rows each), waves 8-15 = h1.
// 4 waves/SIMD; 32-step shared-A chains; TILED h layout -> coalesced A-loads.
__global__ __launch_bounds__(NT, 1) void k_main(
    const bf16* __restrict__ WT, const bf16* __restrict__ GX1,
    bf16* __restrict__ h0b, bf16* __restrict__ h1b, int* __restrict__ cnt,
    const float* __restrict__ bh1, const float* __restrict__ bx2,
    const float* __restrict__ bh2, const float* __restrict__ Wf,
    const float* __restrict__ bfp, float* __restrict__ out) {
  extern __shared__ char lds[];
  bf16* Wlds = (bf16*)lds;
  float* Sx2 = (float*)(lds + LDS_SX2_OFF);   // [24][132] f32: gx2 handoff
  float* red = (float*)(lds + LDS_RED_OFF);   // 16 floats

  const int tid = threadIdx.x;
  const int w = tid >> 6, l = tid & 63;
  const int lr = l & 15, lq = l >> 4;
  const int c0 = blockIdx.x * 8;              // this block's h-column base
  const int koff = ((blockIdx.x >> 3) & 15) * 2;  // XCD-local K-walk stagger

  // tiled-layout write base offset for this block's columns (col>>5 is
  // block-constant: c0 multiple of 8, lr<8 never crosses the 32-boundary)
  const int wr_kq = (c0 >> 5) * 512 + (c0 & 31);

  // ---- stage 72 weight slots into LDS (bf16, k-contiguous, XOR-swizzled) ----
  for (int u = tid; u < 9216; u += NT) {      // 72 slots * 128 granules
    int chunk = u & 127;
    int sid = u >> 7;
    int mat, gcol;
    if (sid < 16)      { mat = 0; gcol = c0 + (sid & 7) + ((sid >> 3) << 10); }
    else if (sid < 32) { int s = sid - 16; mat = 1; gcol = c0 + (s & 7) + ((s >> 3) << 10); }
    else if (sid < 56) { int s = sid - 32; mat = 2; gcol = c0 + (s & 7) + ((s >> 3) << 10); }
    else               { int s = sid - 56; mat = (s < 8) ? 0 : 1; gcol = 2 * U + c0 + (s & 7); }
    bf16x8 v = *(const bf16x8*)(WT + ((size_t)mat * U3 + gcol) * U + chunk * 8);
    *(bf16x8*)(Wlds + ((size_t)sid << 10) + ((chunk ^ (sid & 7) ^ (sid & 8)) << 3)) = v;
  }
  __syncthreads();

  // ---- per-lane biases ----
  const int zr_idx = (lr < 8) ? (c0 + lr) : (U + c0 + lr - 8);
  const int n_idx = 2 * U + c0 + (lr & 7);
  const float bzr1 = bh1[zr_idx];
  const float bhn1 = bh1[n_idx];
  const float bzr2 = bx2[zr_idx] + bh2[zr_idx];
  const float bxn2 = bx2[n_idx];
  const float bhn2 = bh2[n_idx];

  float hm[4];                                // fp32 master state slice (role-owned)
  #pragma unroll
  for (int q = 0; q < 4; ++q) hm[q] = 0.f;

  for (int i = 0; i <= T_SEQ; ++i) {
    // deep buffers: iter i reads h0b[i], h1b[i-1]; writes h0b[i+1], h1b[i].
    const bf16* h0r = h0b + (size_t)i * HBUF_ELEMS;
    const bf16* h1r = h1b + (size_t)(i > 0 ? i - 1 : 0) * HBUF_ELEMS;
    bf16* h0w = h0b + (size_t)(i + 1) * HBUF_ELEMS;
    bf16* h1w = h1b + (size_t)i * HBUF_ELEMS;

    f32x4 a3zr = {}, a3n = {};

    if (w < 8) {
      // ===== h0-waves: gh1-zr + gx2-zr + combined-n (shared A = H0[i-1]) =====
      f32x4 a1zr = {}, a2zr = {}, an = {};

      // hoist GX1 gate loads (precomputed, barrier-independent)
      bf16x4 g4p = {}, gnp = {};
      if (i < T_SEQ) {
        const bf16* gx = GX1 + (size_t)i * U3 * 128;
        int r0 = w * 16 + lq * 4;
        g4p = *(const bf16x4*)(gx + (size_t)zr_idx * 128 + r0);
        gnp = *(const bf16x4*)(gx + (size_t)(2 * U + c0 + (lr & 7)) * 128 + r0);
      }

      // tiled layout: wave w's A-panel is tile w; step kss reads ONE
      // contiguous 1KB segment (lanes cover elems 0..511 permuted).
      const bf16* abase = h0r + w * 16384 + lr * 32 + lq * 8;
      #pragma unroll 8
      for (int ks = 0; ks < 32; ++ks) {
        int kss = (ks + koff) & 31;            // XCD-local staggered K-walk
        bf16x8 A = *(const bf16x8*)(abase + kss * 512);
        int k8 = kss * 4 + lq;
        bf16x8 B1zr = ldsw(Wlds, lr, k8);
        bf16x8 B2zr = ldsw(Wlds, 16 + lr, k8);
        bf16x8 Bn   = ldsw(Wlds, 56 + lr, k8);   // lr<8: Wh1-n, lr>=8: Wx2-n
        a1zr = __builtin_amdgcn_mfma_f32_16x16x32_bf16(A, B1zr, a1zr, 0, 0, 0);
        a2zr = __builtin_amdgcn_mfma_f32_16x16x32_bf16(A, B2zr, a2zr, 0, 0, 0);
        an   = __builtin_amdgcn_mfma_f32_16x16x32_bf16(A, Bn,   an,   0, 0, 0);
      }
      // deposit gx2 for the h1-waves: zr from all lanes, n from lanes lr>=8
      {
        int r0 = w * 16 + lq * 4;
        *(f32x4*)(Sx2 + lr * 132 + r0) = a2zr;
        if (lr >= 8) *(f32x4*)(Sx2 + (16 + (lr - 8)) * 132 + r0) = an;
      }
      // h0 update: H0[i] = GRU1(H0[i-1], x[i])
      if (i < T_SEQ) {
        f32x4 sv;
        #pragma unroll
        for (int j = 0; j < 4; ++j) sv[j] = sigmoidf_(a1zr[j] + bzr1 + (float)g4p[j]);
        f32x4 rv;
        #pragma unroll
        for (int j = 0; j < 4; ++j) rv[j] = __shfl_xor(sv[j], 8);
        if (lr < 8) {
          #pragma unroll
          for (int j = 0; j < 4; ++j) {
            float nn = tanhf((float)gnp[j] + rv[j] * (an[j] + bhn1));
            float z = sv[j];
            float h = z * hm[j] + (1.f - z) * nn;
            hm[j] = h;
            // tiled write: tile w, row-in-tile = lq*4+j, kin = (c0&31)+lr
            st_pair(h0w + w * 16384 + wr_kq + (lq * 4 + j) * 32 + (lr & ~1), lr, h);
          }
        }
      }
    } else if (i > 0) {
      // ===== h1-waves: gh2 = H1[i-2]@Wh2 =====
      const bf16* abase = h1r + (w - 8) * 16384 + lr * 32 + lq * 8;
      #pragma unroll 8
      for (int ks = 0; ks < 32; ++ks) {
        int kss = (ks + koff) & 31;
        bf16x8 A = *(const bf16x8*)(abase + kss * 512);
        int k8 = kss * 4 + lq;
        bf16x8 B3zr = ldsw(Wlds, 32 + lr, k8);
        bf16x8 B3n  = ldsw(Wlds, 48 + (lr & 7), k8);
        a3zr = __builtin_amdgcn_mfma_f32_16x16x32_bf16(A, B3zr, a3zr, 0, 0, 0);
        a3n  = __builtin_amdgcn_mfma_f32_16x16x32_bf16(A, B3n,  a3n, 0, 0, 0);
      }
    }
    __syncthreads();   // gx2 handoff visible to h1-waves
    if (w >= 8 && i > 0) {
      // h1 update: H1[i-1] = GRU2(H1[i-2], H0[i-1])
      int r0 = (w - 8) * 16 + lq * 4;
      f32x4 sv;
      #pragma unroll
      for (int j = 0; j < 4; ++j)
        sv[j] = sigmoidf_(a3zr[j] + bzr2 + Sx2[lr * 132 + r0 + j]);
      f32x4 rv;
      #pragma unroll
      for (int j = 0; j < 4; ++j) rv[j] = __shfl_xor(sv[j], 8);
      if (lr < 8) {
        #pragma unroll
        for (int j = 0; j < 4; ++j) {
          float xn = Sx2[(16 + lr) * 132 + r0 + j] + bxn2;
          float nn = tanhf(xn + rv[j] * (a3n[j] + bhn2));
          float z = sv[j];
          float h = z * hm[j] + (1.f - z) * nn;
          hm[j] = h;
          st_pair(h1w + (w - 8) * 16384 + wr_kq + (lq * 4 + j) * 32 + (lr & ~1), lr, h);
        }
      }
    }
    gridbar(cnt, i);
  }

  // ---- final dense head: out[b] = sigmoid(H1[79] . Wf + bf), block b ----
  {
    const bf16* h1f = h1b + (size_t)T_SEQ * HBUF_ELEMS;
    const int b = blockIdx.x;
    float part = 0.f;
    if (tid < 256) {
      int k0 = tid * 4;
      // tiled layout: elem(b, k0) at (b>>4)*16384 + (k0>>5)*512 + (b&15)*32 + (k0&31)
      const bf16* p = h1f + (b >> 4) * 16384 + (k0 >> 5) * 512 + (b & 15) * 32 + (k0 & 31);
      bf16x4 hv = *(const bf16x4*)p;
      #pragma unroll
      for (int j = 0; j < 4; ++j) part += (float)hv[j] * Wf[k0 + j];
    }
    #pragma unroll
    for (int off = 32; off > 0; off >>= 1) part += __shfl_down(part, off);
    if (l == 0) red[w] = part;
    __syncthreads();
    if (tid == 0) {
      float s = bfp[0];
      #pragma unroll
      for (int q = 0; q < 16; ++q) s += red[q];
      out[blockIdx.x] = sigmoidf_(s);
    }
  }
}

extern "C" void kernel_launch(void* const* d_in, const int* in_sizes, int n_in,
                              void* d_out, int out_size, void* d_ws, size_t ws_size,
                              hipStream_t stream) {
  if (ws_size < WS_NEED) return;  // workspace insufficient -> deliberate clean fail
  const int*   tok = (const int*)d_in[0];
  const float* E   = (const float*)d_in[1];
  const float* Wx1 = (const float*)d_in[2];
  const float* Wh1 = (const float*)d_in[3];
  const float* bx1 = (const float*)d_in[4];
  const float* bh1 = (const float*)d_in[5];
  const float* Wx2 = (const float*)d_in[6];
  const float* Wh2 = (const float*)d_in[7];
  const float* bx2 = (const float*)d_in[8];
  const float* bh2 = (const float*)d_in[9];
  const float* Wf  = (const float*)d_in[10];
  const float* bfp = (const float*)d_in[11];
  char* ws = (char*)d_ws;
  bf16* WT   = (bf16*)(ws + WT_OFF);
  bf16* WXT  = (bf16*)(ws + WXT_OFF);
  bf16* Xg   = (bf16*)(ws + XG_OFF);
  bf16* GX1  = (bf16*)(ws + GX1_OFF);
  bf16* h0b  = (bf16*)(ws + H0B_OFF);
  bf16* h1b  = (bf16*)(ws + H1B_OFF);
  int*  cnt  = (int*)(ws + CNT_OFF);

  // zero only what's read-before-write: h0b[0], h1b[0], counters
  hipMemsetAsync(ws + H0B_OFF, 0, 262144, stream);
  hipMemsetAsync(ws + H1B_OFF, 0, 262144, stream);
  hipMemsetAsync(ws + CNT_OFF, 0, 2048, stream);
  k_embed<<<dim3(5120), dim3(256), 0, stream>>>(tok, E, Xg);
  k_trans<<<dim3(96, 32, 3), dim3(32, 8), 0, stream>>>(Wh1, Wx2, Wh2, WT);
  k_wxt<<<dim3(96, 4), dim3(32, 8), 0, stream>>>(Wx1, WXT);
  k_gx1<<<dim3(160, 48), dim3(256), 0, stream>>>(Xg, WXT, bx1, GX1);
  hipFuncSetAttribute((const void*)k_main, hipFuncAttributeMaxDynamicSharedMemorySize, LDS_BYTES);
  k_main<<<dim3(NB), dim3(NT), LDS_BYTES, stream>>>(WT, GX1, h0b, h1b, cnt,
                                                    bh1, bx2, bh2, Wf, bfp, (float*)d_out);
}